// Round 10
// baseline (187.946 us; speedup 1.0000x reference)
//
#include <hip/hip_runtime.h>
#include <hip/hip_bf16.h>

#define DD 64
#define CHUNK 128   // edges per stage buffer (32KB f32)
#define NEB 256     // edgesum blocks (1 per CU)
#define GB 256      // graph bins (B==256)
#define MAXPER 3136 // >= ceil(E/NEB) edges per block, padded

typedef __attribute__((ext_vector_type(8))) short bf16x8_t;
typedef __attribute__((ext_vector_type(4))) float f32x4_t;
typedef __attribute__((address_space(3))) uint32_t lds_u32;
typedef const __attribute__((address_space(1))) uint32_t glb_u32;

__device__ __forceinline__ ushort f2b(float x) {
  __hip_bfloat16 h = __float2bfloat16(x);
  ushort r;
  __builtin_memcpy(&r, &h, 2);
  return r;
}

__global__ __launch_bounds__(256) void k_zero(int* __restrict__ p, int n) {
  int gid = blockIdx.x * blockDim.x + threadIdx.x;
  int stride = gridDim.x * blockDim.x;
  for (int i = gid; i < n; i += stride) p[i] = 0;
}

__global__ __launch_bounds__(256) void k_hist(const int* __restrict__ eidx,
                                              int* __restrict__ cnt, int E) {
  int gid = blockIdx.x * blockDim.x + threadIdx.x;
  int stride = gridDim.x * blockDim.x;
  int E4 = E >> 2;
  const int4* e4 = reinterpret_cast<const int4*>(eidx);
  for (int i = gid; i < E4; i += stride) {
    int4 v = e4[i];
    atomicAdd(&cnt[v.x], 1);
    atomicAdd(&cnt[v.y], 1);
    atomicAdd(&cnt[v.z], 1);
    atomicAdd(&cnt[v.w], 1);
  }
  for (int e = (E4 << 2) + gid; e < E; e += stride) atomicAdd(&cnt[eidx[e]], 1);
}

// ---------------------------------------------------------------------------
// Direct edge -> graph-bin accumulation.
//  * ALL meta (graph id, weight) for this block's 3125-edge range precomputed
//    once into LDS at entry: random cnt/batch lookups overlap massively,
//    instead of serializing 2 dependent random loads inside every chunk phase.
//  * Payload staged via global_load_lds, double-buffered, 1 barrier/chunk.
//  * Wave w owns graph bins [32w,32w+32): private LDS region, zero atomics.
//  * Partial written TRANSPOSED: partial[(g*NEB + blk)*DD + d] so k_reduce
//    reads contiguous 64KB per graph.
// LDS: 64 (stage x2) + 64 (acc) + 24.5 (meta) = 152.5 KB -> 1 block/CU.
// ---------------------------------------------------------------------------
__global__ __launch_bounds__(512) void k_edgesum(const float* __restrict__ edge_attr,
                                                 const int* __restrict__ eidx,
                                                 const int* __restrict__ cnt,
                                                 const int* __restrict__ batch,
                                                 float* __restrict__ partial, int E) {
  __shared__ float stage[2][CHUNK * DD];  // 2 x 32 KB
  __shared__ float acc[GB * DD];          // 64 KB
  __shared__ int2 meta[MAXPER];           // 24.5 KB
  const int tid = threadIdx.x;
  const int lane = tid & 63, wv = tid >> 6;

  const int per = (E + NEB - 1) / NEB;
  const int base = blockIdx.x * per;
  const int nE = max(0, min(per, E - base));
  const int nch = (nE + CHUNK - 1) / CHUNK;

  for (int i = tid; i < GB * DD; i += 512) acc[i] = 0.f;
  // precompute all meta for this block's edge range (independent random loads)
  for (int i = tid; i < MAXPER; i += 512) {
    int pb = -1;
    float pw = 0.f;
    if (i < nE) {
      int n = eidx[base + i];
      pw = 1.0f / fmaxf((float)cnt[n], 1.0f);
      pb = batch[n];
    }
    meta[i].x = pb;
    meta[i].y = __float_as_int(pw);
  }

  auto issue_stage = [&](int c, int buf) {
    int off = c * CHUNK;
    int m = min(CHUNK, nE - off);
    const float* gsrc = edge_attr + (size_t)(base + off) * DD;
    if (m == CHUNK) {
#pragma unroll
      for (int k = 0; k < 4; ++k) {
        const float* src = gsrc + wv * 1024 + k * 256 + lane * 4;  // per-lane
        float* dst = &stage[buf][wv * 1024 + k * 256];             // uniform
        __builtin_amdgcn_global_load_lds((glb_u32*)src, (lds_u32*)dst, 16, 0, 0);
      }
    } else {
      for (int i = tid; i < m * 16; i += 512) {
        int row = i >> 4, q = i & 15;
        float4 v = *reinterpret_cast<const float4*>(gsrc + row * DD + q * 4);
        *reinterpret_cast<float4*>(&stage[buf][row * DD + q * 4]) = v;
      }
    }
  };

  if (nch > 0) issue_stage(0, 0);
  __syncthreads();  // meta complete + stage0 complete (vmcnt drained)
  for (int c = 0; c < nch; ++c) {
    int cur = c & 1, nxt = cur ^ 1;
    if (c + 1 < nch) issue_stage(c + 1, nxt);
    // process stage[cur]
#pragma unroll
    for (int h = 0; h < CHUNK / 64; ++h) {
      int2 mm = meta[c * CHUNK + h * 64 + lane];
      int b = mm.x;
      float w = __int_as_float(mm.y);
      bool mine = (b >= 0) && ((b >> 5) == wv);
      unsigned long long mask = __ballot(mine);
      while (mask) {
        int i = __ffsll((unsigned long long)mask) - 1;
        mask &= mask - 1;
        int bb = __shfl(b, i);
        float ww = __shfl(w, i);
        float v = stage[cur][(h * 64 + i) * DD + lane];  // lane = dim, stride-1
        acc[bb * DD + lane] += v * ww;                   // wave-private bin
      }
    }
    __syncthreads();  // stage[nxt] complete; stage[cur] free for next issue
  }
  // transposed partial: [g][blk][d]
  for (int i = tid; i < GB * DD; i += 512) {
    int g = i >> 6, d = i & 63;
    partial[((size_t)g * NEB + blockIdx.x) * DD + d] = acc[i];
  }
}

// ---------------------------------------------------------------------------
// Per-graph: reduce NEB partials (CONTIGUOUS 64KB per graph) + pool x + copy
// u -> bf16 comb row.
// ---------------------------------------------------------------------------
__global__ __launch_bounds__(256) void k_reduce(const float* __restrict__ partial,
                                                const float* __restrict__ x,
                                                const float* __restrict__ u,
                                                const int* __restrict__ batch,
                                                ushort* __restrict__ comb, int N) {
  __shared__ int s_lo, s_hi;
  __shared__ float rE[4][64], rV[4][64];
  int b = blockIdx.x;
  int tid = threadIdx.x;
  if (tid == 0) {
    int lo = 0, hi = N;
    while (lo < hi) { int m = (lo + hi) >> 1; if (batch[m] < b) lo = m + 1; else hi = m; }
    s_lo = lo;
    hi = N;
    while (lo < hi) { int m = (lo + hi) >> 1; if (batch[m] < b + 1) lo = m + 1; else hi = m; }
    s_hi = lo;
  }
  __syncthreads();
  int lo = s_lo, hi = s_hi;
  int d = tid & 63, sub = tid >> 6;
  float accE = 0.f, accV = 0.f;
  const float* pb = partial + (size_t)b * NEB * DD;
  for (int p = sub; p < NEB; p += 4)
    accE += pb[p * DD + d];  // contiguous 1KB per block-iteration
  for (int n = lo + sub; n < hi; n += 4)
    accV += x[(size_t)n * DD + d];
  rE[sub][d] = accE;
  rV[sub][d] = accV;
  __syncthreads();
  if (sub == 0) {
    float invNb = 1.0f / fmaxf((float)(hi - lo), 1.0f);
    float ue = (rE[0][d] + rE[1][d] + rE[2][d] + rE[3][d]) * invNb;
    float uv = (rV[0][d] + rV[1][d] + rV[2][d] + rV[3][d]) * invNb;
    ushort* row = comb + (size_t)b * 192;
    row[d] = f2b(ue);
    row[64 + d] = f2b(uv);
    row[128 + d] = f2b(u[(size_t)b * DD + d]);
  }
}

// ---------------------------------------------------------------------------
// MFMA MLP: 1 block, 512 threads (8 waves), all weights pre-staged behind one
// barrier. Proven (absmax 0.039 << 0.13).
// ---------------------------------------------------------------------------
template <int K, int WS, bool FIRST, bool LAST>
__device__ __forceinline__ void mlp_layer(int tid, const ushort* __restrict__ combg,
                                          float* hbuf, ushort* a_lds,
                                          const ushort* w_lds, const float* bias_s,
                                          float* ps, float* pq, float* ab, float* bb,
                                          const float* __restrict__ gamma,
                                          const float* __restrict__ beta,
                                          float* __restrict__ out) {
  const int lane = tid & 63, wv = tid >> 6;
  f32x4_t acc[2][4];
#pragma unroll
  for (int a = 0; a < 2; ++a)
#pragma unroll
    for (int nt = 0; nt < 4; ++nt) acc[a][nt] = (f32x4_t)(0.0f);

  const int m0 = wv * 32;
  const int r15 = lane & 15, kq = lane >> 4;
  for (int kk = 0; kk < K; kk += 32) {
    int koff = kk + kq * 8;
    bf16x8_t af[2], bf[4];
    if (FIRST) {
      const ushort* ap = combg + (size_t)(m0 + r15) * 192 + koff;
      af[0] = *reinterpret_cast<const bf16x8_t*>(ap);
      af[1] = *reinterpret_cast<const bf16x8_t*>(ap + 16 * 192);
    } else {
      const ushort* ap = &a_lds[(m0 + r15) * 72 + koff];
      af[0] = *reinterpret_cast<const bf16x8_t*>(ap);
      af[1] = *reinterpret_cast<const bf16x8_t*>(ap + 16 * 72);
    }
#pragma unroll
    for (int nt = 0; nt < 4; ++nt)
      bf[nt] = *reinterpret_cast<const bf16x8_t*>(&w_lds[(nt * 16 + r15) * WS + koff]);
#pragma unroll
    for (int a = 0; a < 2; ++a)
#pragma unroll
      for (int nt = 0; nt < 4; ++nt)
        acc[a][nt] = __builtin_amdgcn_mfma_f32_16x16x32_bf16(af[a], bf[nt], acc[a][nt], 0, 0, 0);
  }

#pragma unroll
  for (int a = 0; a < 2; ++a) {
#pragma unroll
    for (int nt = 0; nt < 4; ++nt) {
      int col = nt * 16 + r15;
#pragma unroll
      for (int j = 0; j < 4; ++j) {
        int row = m0 + a * 16 + kq * 4 + j;
        float v = acc[a][nt][j] + bias_s[col];
        hbuf[row * 65 + col] = fmaxf(v, 0.f);
      }
    }
  }
  __syncthreads();

  {
    int col = tid & 63, seg = tid >> 6;
    float s = 0.f, q = 0.f;
#pragma unroll
    for (int t = 0; t < 32; ++t) {
      float v = hbuf[(seg * 32 + t) * 65 + col];
      s += v;
      q += v * v;
    }
    ps[seg * 64 + col] = s;
    pq[seg * 64 + col] = q;
  }
  __syncthreads();
  if (tid < 64) {
    float s = 0.f, q = 0.f;
#pragma unroll
    for (int g = 0; g < 8; ++g) {
      s += ps[g * 64 + tid];
      q += pq[g * 64 + tid];
    }
    float mu = s * (1.0f / 256.0f);
    float var = q * (1.0f / 256.0f) - mu * mu;
    float rs = rsqrtf(var + 1e-5f);
    float A = gamma[tid] * rs;
    ab[tid] = A;
    bb[tid] = beta[tid] - mu * A;
  }
  __syncthreads();
  for (int i = tid; i < 256 * 64; i += 512) {
    int r = i >> 6, c = i & 63;
    float y = hbuf[r * 65 + c] * ab[c] + bb[c];
    if (LAST)
      out[i] = y;
    else
      a_lds[r * 72 + c] = f2b(y);
  }
  __syncthreads();
}

__global__ __launch_bounds__(512) void k_mlp(const ushort* __restrict__ comb,
                                             const float* W0, const float* b0,
                                             const float* W1, const float* b1,
                                             const float* W2, const float* b2,
                                             const float* g0, const float* be0,
                                             const float* g1, const float* be1,
                                             const float* g2, const float* be2,
                                             float* __restrict__ out) {
  __shared__ __align__(16) float hbuf[256 * 65];    // 66.6 KB
  __shared__ __align__(16) ushort a_lds[256 * 72];  // 36.9 KB
  __shared__ __align__(16) ushort w0s[64 * 200];    // 25.6 KB
  __shared__ __align__(16) ushort w1s[64 * 72];     // 9.2 KB
  __shared__ __align__(16) ushort w2s[64 * 72];     // 9.2 KB
  __shared__ float ps[8 * 64], pq[8 * 64];
  __shared__ float b0s[64], b1s[64], b2s[64], ab[64], bb[64];
  int tid = threadIdx.x;

  for (int i = tid; i < 64 * 192; i += 512) {
    int r = i / 192, c = i - r * 192;
    w0s[r * 200 + c] = f2b(W0[i]);
  }
  for (int i = tid; i < 64 * 64; i += 512) {
    int r = i >> 6, c = i & 63;
    w1s[r * 72 + c] = f2b(W1[i]);
    w2s[r * 72 + c] = f2b(W2[i]);
  }
  if (tid < 64) {
    b0s[tid] = b0[tid];
    b1s[tid] = b1[tid];
    b2s[tid] = b2[tid];
  }
  __syncthreads();

  mlp_layer<192, 200, true, false>(tid, comb, hbuf, a_lds, w0s, b0s, ps, pq, ab, bb,
                                   g0, be0, nullptr);
  mlp_layer<64, 72, false, false>(tid, comb, hbuf, a_lds, w1s, b1s, ps, pq, ab, bb,
                                  g1, be1, nullptr);
  mlp_layer<64, 72, false, true>(tid, comb, hbuf, a_lds, w2s, b2s, ps, pq, ab, bb,
                                 g2, be2, out);
}

extern "C" void kernel_launch(void* const* d_in, const int* in_sizes, int n_in,
                              void* d_out, int out_size, void* d_ws, size_t ws_size,
                              hipStream_t stream) {
  (void)n_in; (void)out_size; (void)ws_size;
  const float* x         = (const float*)d_in[0];
  const float* edge_attr = (const float*)d_in[1];
  const float* u         = (const float*)d_in[2];
  const int*   eidx      = (const int*)d_in[3];  // row 0 = first E entries
  const int*   batch     = (const int*)d_in[4];
  const float* W0 = (const float*)d_in[5];
  const float* b0 = (const float*)d_in[6];
  const float* W1 = (const float*)d_in[7];
  const float* b1 = (const float*)d_in[8];
  const float* W2 = (const float*)d_in[9];
  const float* b2 = (const float*)d_in[10];
  const float* g0 = (const float*)d_in[11];
  const float* be0 = (const float*)d_in[12];
  const float* g1 = (const float*)d_in[13];
  const float* be1 = (const float*)d_in[14];
  const float* g2 = (const float*)d_in[15];
  const float* be2 = (const float*)d_in[16];

  int N = in_sizes[0] / DD;
  int E = in_sizes[1] / DD;

  // ws layout (16B padded): partial[GB*NEB*64] f32 (16.7MB) | cnt[N] | comb
  float* partial = (float*)d_ws;
  int* cnt = (int*)(partial + (size_t)GB * NEB * DD);
  ushort* comb = (ushort*)(cnt + ((N + 3) & ~3));

  k_zero<<<64, 256, 0, stream>>>(cnt, N);
  k_hist<<<1024, 256, 0, stream>>>(eidx, cnt, E);
  k_edgesum<<<NEB, 512, 0, stream>>>(edge_attr, eidx, cnt, batch, partial, E);
  k_reduce<<<256, 256, 0, stream>>>(partial, x, u, batch, comb, N);
  k_mlp<<<1, 512, 0, stream>>>(comb, W0, b0, W1, b1, W2, b2,
                               g0, be0, g1, be1, g2, be2, (float*)d_out);
}

// Round 11
// 170.347 us; speedup vs baseline: 1.1033x; 1.1033x over previous
//
#include <hip/hip_runtime.h>
#include <hip/hip_bf16.h>

#define DD 64
#define CHUNK 64    // edges per stage buffer (16KB f32)
#define NBUF 4      // stage buffers (counted-vmcnt pipeline)
#define NEB 256     // edgesum blocks (1 per CU)
#define GB 256      // graph bins (B==256)
#define MAXPER 3136 // >= ceil(E/NEB), multiple of CHUNK

typedef __attribute__((ext_vector_type(8))) short bf16x8_t;
typedef __attribute__((ext_vector_type(4))) float f32x4_t;
typedef __attribute__((address_space(3))) uint32_t lds_u32;
typedef const __attribute__((address_space(1))) uint32_t glb_u32;

__device__ __forceinline__ ushort f2b(float x) {
  __hip_bfloat16 h = __float2bfloat16(x);
  ushort r;
  __builtin_memcpy(&r, &h, 2);
  return r;
}

__global__ __launch_bounds__(256) void k_zero(int* __restrict__ p, int n) {
  int gid = blockIdx.x * blockDim.x + threadIdx.x;
  int stride = gridDim.x * blockDim.x;
  for (int i = gid; i < n; i += stride) p[i] = 0;
}

__global__ __launch_bounds__(256) void k_hist(const int* __restrict__ eidx,
                                              int* __restrict__ cnt, int E) {
  int gid = blockIdx.x * blockDim.x + threadIdx.x;
  int stride = gridDim.x * blockDim.x;
  int E4 = E >> 2;
  const int4* e4 = reinterpret_cast<const int4*>(eidx);
  for (int i = gid; i < E4; i += stride) {
    int4 v = e4[i];
    atomicAdd(&cnt[v.x], 1);
    atomicAdd(&cnt[v.y], 1);
    atomicAdd(&cnt[v.z], 1);
    atomicAdd(&cnt[v.w], 1);
  }
  for (int e = (E4 << 2) + gid; e < E; e += stride) atomicAdd(&cnt[eidx[e]], 1);
}

// ---------------------------------------------------------------------------
// Direct edge -> graph-bin accumulation, counted-vmcnt pipelined staging.
//  * meta (graph id, weight) precomputed ONCE into LDS (needed so the main
//    loop's vmcnt counts only the 2 gload_lds per wave per chunk).
//  * 4 stage buffers; prologue issues 3 chunks; per iter:
//      s_waitcnt vmcnt(4)  -> chunk c resident (2 chunks may stay in flight)
//      s_barrier           -> all waves' slices visible
//      process c; issue c+3 (buffer (c-1)%4: all waves passed bar after
//                            processing c-1, so reuse is safe)
//    HBM pipe never drains (vs __syncthreads vmcnt(0) drain costing ~6600
//    cyc/chunk at R9).
//  * Wave w owns graph bins [32w,32w+32): private LDS region, zero atomics.
//  * Partial written contiguous per block (R9 layout [blk][g][d]).
// LDS: 64 (stage x4) + 64 (acc) + 24.5 (meta) = 152.5 KB -> 1 block/CU.
// ---------------------------------------------------------------------------
__global__ __launch_bounds__(512) void k_edgesum(const float* __restrict__ edge_attr,
                                                 const int* __restrict__ eidx,
                                                 const int* __restrict__ cnt,
                                                 const int* __restrict__ batch,
                                                 float* __restrict__ partial, int E) {
  __shared__ float stage[NBUF][CHUNK * DD];  // 4 x 16 KB
  __shared__ float acc[GB * DD];             // 64 KB
  __shared__ int2 meta[MAXPER];              // 24.5 KB
  const int tid = threadIdx.x;
  const int lane = tid & 63, wv = tid >> 6;

  const int per = (E + NEB - 1) / NEB;
  const int base = blockIdx.x * per;
  const int nE = max(0, min(per, E - base));
  const int nfull = nE / CHUNK;
  const int tail = nE - nfull * CHUNK;

  for (int i = tid; i < GB * DD; i += 512) acc[i] = 0.f;
  // one-time meta precompute: independent random loads, latency amortized
  for (int i = tid; i < MAXPER; i += 512) {
    int pb = -1;
    float pw = 0.f;
    if (i < nE) {
      int n = eidx[base + i];
      pw = 1.0f / fmaxf((float)cnt[n], 1.0f);
      pb = batch[n];
    }
    meta[i] = make_int2(pb, __float_as_int(pw));
  }

  // stage full chunk c into buffer c%NBUF: per wave 2 x gload_lds of 1KB
  // (rows [wv*8, wv*8+8); dst wave-uniform, HW adds lane*16B)
  auto issue = [&](int c) {
    const float* gsrc = edge_attr + ((size_t)(base + c * CHUNK) + wv * 8) * DD;
    float* dst = &stage[c & (NBUF - 1)][wv * 8 * DD];
#pragma unroll
    for (int k = 0; k < 2; ++k)
      __builtin_amdgcn_global_load_lds((glb_u32*)(gsrc + k * 256 + lane * 4),
                                       (lds_u32*)(dst + k * 256), 16, 0, 0);
  };

  __syncthreads();  // meta+acc ready; drains meta vmem loads (clean vmcnt)
  if (nfull > 0) issue(0);
  if (nfull > 1) issue(1);
  if (nfull > 2) issue(2);
  for (int c = 0; c < nfull; ++c) {
    asm volatile("s_waitcnt vmcnt(4)" ::: "memory");  // chunk c resident (mine)
    __builtin_amdgcn_s_barrier();                     // everyone's slice resident
    __builtin_amdgcn_sched_barrier(0);
    {
      int2 mm = meta[c * CHUNK + lane];
      int b = mm.x;
      float w = __int_as_float(mm.y);
      bool mine = (b >= 0) && ((b >> 5) == wv);
      unsigned long long mask = __ballot(mine);
      const float* sb = &stage[c & (NBUF - 1)][0];
      while (mask) {
        int i = __ffsll(mask) - 1;
        mask &= mask - 1;
        int bb = __shfl(b, i);
        float ww = __shfl(w, i);
        acc[bb * DD + lane] += sb[i * DD + lane] * ww;  // wave-private bin
      }
    }
    __builtin_amdgcn_sched_barrier(0);
    if (c + 3 < nfull) issue(c + 3);
  }
  // tail (<CHUNK edges): plain staged path
  __syncthreads();
  if (tail > 0) {
    const float* gsrc = edge_attr + (size_t)(base + nfull * CHUNK) * DD;
    for (int i = tid; i < tail * 16; i += 512) {
      int row = i >> 4, q = i & 15;
      float4 v = *reinterpret_cast<const float4*>(gsrc + row * DD + q * 4);
      *reinterpret_cast<float4*>(&stage[0][row * DD + q * 4]) = v;
    }
    __syncthreads();
    int2 mm = make_int2(-1, 0);
    if (lane < tail) mm = meta[nfull * CHUNK + lane];
    int b = mm.x;
    float w = __int_as_float(mm.y);
    bool mine = (b >= 0) && ((b >> 5) == wv);
    unsigned long long mask = __ballot(mine);
    while (mask) {
      int i = __ffsll(mask) - 1;
      mask &= mask - 1;
      int bb = __shfl(b, i);
      float ww = __shfl(w, i);
      acc[bb * DD + lane] += stage[0][i * DD + lane] * ww;
    }
  }
  __syncthreads();
  float* out = partial + (size_t)blockIdx.x * GB * DD;  // contiguous 64KB
  for (int i = tid; i < GB * DD; i += 512) out[i] = acc[i];
}

// ---------------------------------------------------------------------------
// Per-graph: reduce NEB partials + pool x + copy u -> bf16 comb row (R9).
// ---------------------------------------------------------------------------
__global__ __launch_bounds__(256) void k_reduce(const float* __restrict__ partial,
                                                const float* __restrict__ x,
                                                const float* __restrict__ u,
                                                const int* __restrict__ batch,
                                                ushort* __restrict__ comb, int N) {
  __shared__ int s_lo, s_hi;
  __shared__ float rE[4][64], rV[4][64];
  int b = blockIdx.x;
  int tid = threadIdx.x;
  if (tid == 0) {
    int lo = 0, hi = N;
    while (lo < hi) { int m = (lo + hi) >> 1; if (batch[m] < b) lo = m + 1; else hi = m; }
    s_lo = lo;
    hi = N;
    while (lo < hi) { int m = (lo + hi) >> 1; if (batch[m] < b + 1) lo = m + 1; else hi = m; }
    s_hi = lo;
  }
  __syncthreads();
  int lo = s_lo, hi = s_hi;
  int d = tid & 63, sub = tid >> 6;
  float accE = 0.f, accV = 0.f;
  for (int p = sub; p < NEB; p += 4)
    accE += partial[((size_t)p * GB + b) * DD + d];
  for (int n = lo + sub; n < hi; n += 4)
    accV += x[(size_t)n * DD + d];
  rE[sub][d] = accE;
  rV[sub][d] = accV;
  __syncthreads();
  if (sub == 0) {
    float invNb = 1.0f / fmaxf((float)(hi - lo), 1.0f);
    float ue = (rE[0][d] + rE[1][d] + rE[2][d] + rE[3][d]) * invNb;
    float uv = (rV[0][d] + rV[1][d] + rV[2][d] + rV[3][d]) * invNb;
    ushort* row = comb + (size_t)b * 192;
    row[d] = f2b(ue);
    row[64 + d] = f2b(uv);
    row[128 + d] = f2b(u[(size_t)b * DD + d]);
  }
}

// ---------------------------------------------------------------------------
// MFMA MLP: 1 block, 512 threads (8 waves), all weights pre-staged behind one
// barrier. Proven (absmax 0.039 << 0.13).
// ---------------------------------------------------------------------------
template <int K, int WS, bool FIRST, bool LAST>
__device__ __forceinline__ void mlp_layer(int tid, const ushort* __restrict__ combg,
                                          float* hbuf, ushort* a_lds,
                                          const ushort* w_lds, const float* bias_s,
                                          float* ps, float* pq, float* ab, float* bb,
                                          const float* __restrict__ gamma,
                                          const float* __restrict__ beta,
                                          float* __restrict__ out) {
  const int lane = tid & 63, wv = tid >> 6;
  f32x4_t acc[2][4];
#pragma unroll
  for (int a = 0; a < 2; ++a)
#pragma unroll
    for (int nt = 0; nt < 4; ++nt) acc[a][nt] = (f32x4_t)(0.0f);

  const int m0 = wv * 32;
  const int r15 = lane & 15, kq = lane >> 4;
  for (int kk = 0; kk < K; kk += 32) {
    int koff = kk + kq * 8;
    bf16x8_t af[2], bf[4];
    if (FIRST) {
      const ushort* ap = combg + (size_t)(m0 + r15) * 192 + koff;
      af[0] = *reinterpret_cast<const bf16x8_t*>(ap);
      af[1] = *reinterpret_cast<const bf16x8_t*>(ap + 16 * 192);
    } else {
      const ushort* ap = &a_lds[(m0 + r15) * 72 + koff];
      af[0] = *reinterpret_cast<const bf16x8_t*>(ap);
      af[1] = *reinterpret_cast<const bf16x8_t*>(ap + 16 * 72);
    }
#pragma unroll
    for (int nt = 0; nt < 4; ++nt)
      bf[nt] = *reinterpret_cast<const bf16x8_t*>(&w_lds[(nt * 16 + r15) * WS + koff]);
#pragma unroll
    for (int a = 0; a < 2; ++a)
#pragma unroll
      for (int nt = 0; nt < 4; ++nt)
        acc[a][nt] = __builtin_amdgcn_mfma_f32_16x16x32_bf16(af[a], bf[nt], acc[a][nt], 0, 0, 0);
  }

#pragma unroll
  for (int a = 0; a < 2; ++a) {
#pragma unroll
    for (int nt = 0; nt < 4; ++nt) {
      int col = nt * 16 + r15;
#pragma unroll
      for (int j = 0; j < 4; ++j) {
        int row = m0 + a * 16 + kq * 4 + j;
        float v = acc[a][nt][j] + bias_s[col];
        hbuf[row * 65 + col] = fmaxf(v, 0.f);
      }
    }
  }
  __syncthreads();

  {
    int col = tid & 63, seg = tid >> 6;
    float s = 0.f, q = 0.f;
#pragma unroll
    for (int t = 0; t < 32; ++t) {
      float v = hbuf[(seg * 32 + t) * 65 + col];
      s += v;
      q += v * v;
    }
    ps[seg * 64 + col] = s;
    pq[seg * 64 + col] = q;
  }
  __syncthreads();
  if (tid < 64) {
    float s = 0.f, q = 0.f;
#pragma unroll
    for (int g = 0; g < 8; ++g) {
      s += ps[g * 64 + tid];
      q += pq[g * 64 + tid];
    }
    float mu = s * (1.0f / 256.0f);
    float var = q * (1.0f / 256.0f) - mu * mu;
    float rs = rsqrtf(var + 1e-5f);
    float A = gamma[tid] * rs;
    ab[tid] = A;
    bb[tid] = beta[tid] - mu * A;
  }
  __syncthreads();
  for (int i = tid; i < 256 * 64; i += 512) {
    int r = i >> 6, c = i & 63;
    float y = hbuf[r * 65 + c] * ab[c] + bb[c];
    if (LAST)
      out[i] = y;
    else
      a_lds[r * 72 + c] = f2b(y);
  }
  __syncthreads();
}

__global__ __launch_bounds__(512) void k_mlp(const ushort* __restrict__ comb,
                                             const float* W0, const float* b0,
                                             const float* W1, const float* b1,
                                             const float* W2, const float* b2,
                                             const float* g0, const float* be0,
                                             const float* g1, const float* be1,
                                             const float* g2, const float* be2,
                                             float* __restrict__ out) {
  __shared__ __align__(16) float hbuf[256 * 65];    // 66.6 KB
  __shared__ __align__(16) ushort a_lds[256 * 72];  // 36.9 KB
  __shared__ __align__(16) ushort w0s[64 * 200];    // 25.6 KB
  __shared__ __align__(16) ushort w1s[64 * 72];     // 9.2 KB
  __shared__ __align__(16) ushort w2s[64 * 72];     // 9.2 KB
  __shared__ float ps[8 * 64], pq[8 * 64];
  __shared__ float b0s[64], b1s[64], b2s[64], ab[64], bb[64];
  int tid = threadIdx.x;

  for (int i = tid; i < 64 * 192; i += 512) {
    int r = i / 192, c = i - r * 192;
    w0s[r * 200 + c] = f2b(W0[i]);
  }
  for (int i = tid; i < 64 * 64; i += 512) {
    int r = i >> 6, c = i & 63;
    w1s[r * 72 + c] = f2b(W1[i]);
    w2s[r * 72 + c] = f2b(W2[i]);
  }
  if (tid < 64) {
    b0s[tid] = b0[tid];
    b1s[tid] = b1[tid];
    b2s[tid] = b2[tid];
  }
  __syncthreads();

  mlp_layer<192, 200, true, false>(tid, comb, hbuf, a_lds, w0s, b0s, ps, pq, ab, bb,
                                   g0, be0, nullptr);
  mlp_layer<64, 72, false, false>(tid, comb, hbuf, a_lds, w1s, b1s, ps, pq, ab, bb,
                                  g1, be1, nullptr);
  mlp_layer<64, 72, false, true>(tid, comb, hbuf, a_lds, w2s, b2s, ps, pq, ab, bb,
                                 g2, be2, out);
}

extern "C" void kernel_launch(void* const* d_in, const int* in_sizes, int n_in,
                              void* d_out, int out_size, void* d_ws, size_t ws_size,
                              hipStream_t stream) {
  (void)n_in; (void)out_size; (void)ws_size;
  const float* x         = (const float*)d_in[0];
  const float* edge_attr = (const float*)d_in[1];
  const float* u         = (const float*)d_in[2];
  const int*   eidx      = (const int*)d_in[3];  // row 0 = first E entries
  const int*   batch     = (const int*)d_in[4];
  const float* W0 = (const float*)d_in[5];
  const float* b0 = (const float*)d_in[6];
  const float* W1 = (const float*)d_in[7];
  const float* b1 = (const float*)d_in[8];
  const float* W2 = (const float*)d_in[9];
  const float* b2 = (const float*)d_in[10];
  const float* g0 = (const float*)d_in[11];
  const float* be0 = (const float*)d_in[12];
  const float* g1 = (const float*)d_in[13];
  const float* be1 = (const float*)d_in[14];
  const float* g2 = (const float*)d_in[15];
  const float* be2 = (const float*)d_in[16];

  int N = in_sizes[0] / DD;
  int E = in_sizes[1] / DD;

  // ws layout (16B padded): partial[NEB*GB*64] f32 (16.7MB) | cnt[N] | comb
  float* partial = (float*)d_ws;
  int* cnt = (int*)(partial + (size_t)NEB * GB * DD);
  ushort* comb = (ushort*)(cnt + ((N + 3) & ~3));

  k_zero<<<64, 256, 0, stream>>>(cnt, N);
  k_hist<<<1024, 256, 0, stream>>>(eidx, cnt, E);
  k_edgesum<<<NEB, 512, 0, stream>>>(edge_attr, eidx, cnt, batch, partial, E);
  k_reduce<<<256, 256, 0, stream>>>(partial, x, u, batch, comb, N);
  k_mlp<<<1, 512, 0, stream>>>(comb, W0, b0, W1, b1, W2, b2,
                               g0, be0, g1, be1, g2, be2, (float*)d_out);
}

// Round 12
// 142.975 us; speedup vs baseline: 1.3145x; 1.1915x over previous
//
#include <hip/hip_runtime.h>
#include <hip/hip_bf16.h>

#define DD 64
#define ECH 128     // edges per chunk (one-hot GEMM K)
#define NEB 256     // edgesum blocks (1 per CU)
#define GB 256      // graph bins (B==256)
#define MAXPER 3200 // 25 chunks * 128 >= ceil(E/NEB)=3125

typedef __attribute__((ext_vector_type(8))) short bf16x8_t;
typedef __attribute__((ext_vector_type(4))) float f32x4_t;

__device__ __forceinline__ ushort f2b(float x) {
  __hip_bfloat16 h = __float2bfloat16(x);
  ushort r;
  __builtin_memcpy(&r, &h, 2);
  return r;
}

// XOR swizzle for 256B-row LDS tiles: spreads row-strided b128 reads across
// bank groups (T2). row = byte>>8; flips byte bits 4..6, preserves 16B align.
__device__ __forceinline__ uint swz(uint b) { return b ^ ((((b >> 8) & 7u)) << 4); }

__global__ __launch_bounds__(256) void k_zero(int* __restrict__ p, int n) {
  int gid = blockIdx.x * blockDim.x + threadIdx.x;
  int stride = gridDim.x * blockDim.x;
  for (int i = gid; i < n; i += stride) p[i] = 0;
}

__global__ __launch_bounds__(256) void k_hist(const int* __restrict__ eidx,
                                              int* __restrict__ cnt, int E) {
  int gid = blockIdx.x * blockDim.x + threadIdx.x;
  int stride = gridDim.x * blockDim.x;
  int E4 = E >> 2;
  const int4* e4 = reinterpret_cast<const int4*>(eidx);
  for (int i = gid; i < E4; i += stride) {
    int4 v = e4[i];
    atomicAdd(&cnt[v.x], 1);
    atomicAdd(&cnt[v.y], 1);
    atomicAdd(&cnt[v.z], 1);
    atomicAdd(&cnt[v.w], 1);
  }
  for (int e = (E4 << 2) + gid; e < E; e += stride) atomicAdd(&cnt[eidx[e]], 1);
}

// ---------------------------------------------------------------------------
// Edge -> graph-bin accumulation as ONE-HOT GEMM per chunk:
//   C[256 bins][64 dims] += S[256][128] * Vt^T  where S[b][e] = w_e one-hot.
// Replaces the serial per-edge while(mask) LDS-RMW chain (latency-bound,
// ~200 cyc/edge) with 32 MFMA/wave/chunk into register accumulators.
//  * depth-2 register prefetch (static unroll, named rA/rB: spill-proof)
//  * per chunk: transpose-convert regs -> bf16 Vt[d][e] (packed b32 writes);
//    S delta-update: zero prev entry + write new (2 LDS ops per edge-column)
//  * XOR-swizzled S/Vt rows -> conflict-free b128 fragment reads
//  * raw s_barrier + lgkmcnt(0) only (vmcnt never drained -> prefetch lives)
// LDS: S 64KB + Vt 16KB + meta 25.6KB = 105.6KB -> 1 block/CU.
// ---------------------------------------------------------------------------
__global__ __launch_bounds__(512) void k_edgesum(const float* __restrict__ edge_attr,
                                                 const int* __restrict__ eidx,
                                                 const int* __restrict__ cnt,
                                                 const int* __restrict__ batch,
                                                 float* __restrict__ partial, int E) {
  __shared__ ushort S[256 * 128];  // 64 KB, rows = bins, 256B/row
  __shared__ ushort Vt[64 * 128];  // 16 KB, rows = dims,  256B/row
  __shared__ int2 meta[MAXPER];    // 25.6 KB
  const int tid = threadIdx.x;
  const int lane = tid & 63, wv = tid >> 6;
  const int r15 = lane & 15, kq = lane >> 4;

  const int per = (E + NEB - 1) / NEB;        // 3125
  const int base = blockIdx.x * per;
  const int nE = max(0, min(per, E - base));  // 3125 (E=256*3125 exactly)
  const int nch = (nE + ECH - 1) / ECH;       // 25

  const int e0 = (tid >> 3) * 2;  // edge pair owned by this thread
  const int d0 = (tid & 7) * 8;   // dim group owned by this thread

  float4 rA[4], rB[4];  // [0,1]: edge e0 dims d0..+7; [2,3]: edge e0+1

#define LOADC(c, R)                                                              \
  do {                                                                           \
    size_t r0_ = (size_t)min(base + (c)*ECH + e0, E - 1);                        \
    size_t r1_ = (size_t)min(base + (c)*ECH + e0 + 1, E - 1);                    \
    const float4* p0_ = reinterpret_cast<const float4*>(edge_attr + r0_ * DD + d0); \
    const float4* p1_ = reinterpret_cast<const float4*>(edge_attr + r1_ * DD + d0); \
    R[0] = p0_[0];                                                               \
    R[1] = p0_[1];                                                               \
    R[2] = p1_[0];                                                               \
    R[3] = p1_[1];                                                               \
  } while (0)

#define PHASEW(c, R)                                                             \
  do {                                                                           \
    _Pragma("unroll") for (int q = 0; q < 2; ++q) {                              \
      _Pragma("unroll") for (int j = 0; j < 4; ++j) {                            \
        int d_ = d0 + q * 4 + j;                                                 \
        uint w32_ = (uint)f2b(((const float*)&R[q])[j]) |                        \
                    ((uint)f2b(((const float*)&R[2 + q])[j]) << 16);             \
        *(uint*)((char*)Vt + swz(((uint)d_ * 128 + e0) * 2)) = w32_;             \
      }                                                                          \
    }                                                                            \
    if (tid < ECH) {                                                             \
      if (prev >= 0) *(ushort*)((char*)S + swz(((uint)prev * 128 + tid) * 2)) = 0; \
      int2 mm_ = meta[(c)*ECH + tid];                                            \
      if (mm_.x >= 0) {                                                          \
        *(ushort*)((char*)S + swz(((uint)mm_.x * 128 + tid) * 2)) =              \
            f2b(__int_as_float(mm_.y));                                          \
        prev = mm_.x;                                                            \
      } else {                                                                   \
        prev = -1;                                                               \
      }                                                                          \
    }                                                                            \
  } while (0)

#define MFMAP()                                                                  \
  do {                                                                           \
    _Pragma("unroll") for (int ks = 0; ks < 4; ++ks) {                           \
      uint ko_ = (uint)(ks * 32 + kq * 8) * 2;                                   \
      bf16x8_t a0_ = *(const bf16x8_t*)((const char*)S +                         \
                                        swz((uint)(wv * 32 + r15) * 256 + ko_)); \
      bf16x8_t a1_ = *(const bf16x8_t*)((const char*)S +                         \
                                        swz((uint)(wv * 32 + 16 + r15) * 256 + ko_)); \
      bf16x8_t b0_ = *(const bf16x8_t*)((const char*)Vt + swz((uint)(r15)*256 + ko_)); \
      bf16x8_t b1_ = *(const bf16x8_t*)((const char*)Vt +                        \
                                        swz((uint)(16 + r15) * 256 + ko_));      \
      bf16x8_t b2_ = *(const bf16x8_t*)((const char*)Vt +                        \
                                        swz((uint)(32 + r15) * 256 + ko_));      \
      bf16x8_t b3_ = *(const bf16x8_t*)((const char*)Vt +                        \
                                        swz((uint)(48 + r15) * 256 + ko_));      \
      acc[0][0] = __builtin_amdgcn_mfma_f32_16x16x32_bf16(a0_, b0_, acc[0][0], 0, 0, 0); \
      acc[0][1] = __builtin_amdgcn_mfma_f32_16x16x32_bf16(a0_, b1_, acc[0][1], 0, 0, 0); \
      acc[0][2] = __builtin_amdgcn_mfma_f32_16x16x32_bf16(a0_, b2_, acc[0][2], 0, 0, 0); \
      acc[0][3] = __builtin_amdgcn_mfma_f32_16x16x32_bf16(a0_, b3_, acc[0][3], 0, 0, 0); \
      acc[1][0] = __builtin_amdgcn_mfma_f32_16x16x32_bf16(a1_, b0_, acc[1][0], 0, 0, 0); \
      acc[1][1] = __builtin_amdgcn_mfma_f32_16x16x32_bf16(a1_, b1_, acc[1][1], 0, 0, 0); \
      acc[1][2] = __builtin_amdgcn_mfma_f32_16x16x32_bf16(a1_, b2_, acc[1][2], 0, 0, 0); \
      acc[1][3] = __builtin_amdgcn_mfma_f32_16x16x32_bf16(a1_, b3_, acc[1][3], 0, 0, 0); \
    }                                                                            \
  } while (0)

#define LGKM0() asm volatile("s_waitcnt lgkmcnt(0)" ::: "memory")

  f32x4_t acc[2][4];
#pragma unroll
  for (int a = 0; a < 2; ++a)
#pragma unroll
    for (int nt = 0; nt < 4; ++nt) acc[a][nt] = (f32x4_t)(0.0f);

  // prologue: fire chunk 0/1 loads early, then meta + S zero
  LOADC(0, rA);
  if (nch > 1) LOADC(1, rB);
  for (int i = tid; i < 256 * 128 / 2; i += 512) ((uint*)S)[i] = 0u;
  for (int i = tid; i < MAXPER; i += 512) {
    int pb = -1;
    float pw = 0.f;
    if (i < nE) {
      int n = eidx[base + i];
      pw = 1.0f / fmaxf((float)cnt[n], 1.0f);
      pb = batch[n];
    }
    meta[i] = make_int2(pb, __float_as_int(pw));
  }
  int prev = -1;
  __syncthreads();

  for (int c = 0; c < nch; c += 2) {
    PHASEW(c, rA);
    LGKM0();
    __builtin_amdgcn_s_barrier();
    if (c + 2 < nch) LOADC(c + 2, rA);
    MFMAP();
    LGKM0();
    __builtin_amdgcn_s_barrier();
    if (c + 1 < nch) {
      PHASEW(c + 1, rB);
      LGKM0();
      __builtin_amdgcn_s_barrier();
      if (c + 3 < nch) LOADC(c + 3, rB);
      MFMAP();
      LGKM0();
      __builtin_amdgcn_s_barrier();
    }
  }

  // epilogue: register acc -> partial[blk][bin][d] (contiguous 64KB per block)
  float* outp = partial + (size_t)blockIdx.x * GB * DD;
#pragma unroll
  for (int a = 0; a < 2; ++a)
#pragma unroll
    for (int nt = 0; nt < 4; ++nt)
#pragma unroll
      for (int j = 0; j < 4; ++j) {
        int row = wv * 32 + a * 16 + kq * 4 + j;
        int col = nt * 16 + r15;
        outp[row * DD + col] = acc[a][nt][j];
      }
#undef LOADC
#undef PHASEW
#undef MFMAP
#undef LGKM0
}

// ---------------------------------------------------------------------------
// Per-graph: reduce NEB partials + pool x + copy u -> bf16 comb row (R9/R11).
// ---------------------------------------------------------------------------
__global__ __launch_bounds__(256) void k_reduce(const float* __restrict__ partial,
                                                const float* __restrict__ x,
                                                const float* __restrict__ u,
                                                const int* __restrict__ batch,
                                                ushort* __restrict__ comb, int N) {
  __shared__ int s_lo, s_hi;
  __shared__ float rE[4][64], rV[4][64];
  int b = blockIdx.x;
  int tid = threadIdx.x;
  if (tid == 0) {
    int lo = 0, hi = N;
    while (lo < hi) { int m = (lo + hi) >> 1; if (batch[m] < b) lo = m + 1; else hi = m; }
    s_lo = lo;
    hi = N;
    while (lo < hi) { int m = (lo + hi) >> 1; if (batch[m] < b + 1) lo = m + 1; else hi = m; }
    s_hi = lo;
  }
  __syncthreads();
  int lo = s_lo, hi = s_hi;
  int d = tid & 63, sub = tid >> 6;
  float accE = 0.f, accV = 0.f;
  for (int p = sub; p < NEB; p += 4)
    accE += partial[((size_t)p * GB + b) * DD + d];
  for (int n = lo + sub; n < hi; n += 4)
    accV += x[(size_t)n * DD + d];
  rE[sub][d] = accE;
  rV[sub][d] = accV;
  __syncthreads();
  if (sub == 0) {
    float invNb = 1.0f / fmaxf((float)(hi - lo), 1.0f);
    float ue = (rE[0][d] + rE[1][d] + rE[2][d] + rE[3][d]) * invNb;
    float uv = (rV[0][d] + rV[1][d] + rV[2][d] + rV[3][d]) * invNb;
    ushort* row = comb + (size_t)b * 192;
    row[d] = f2b(ue);
    row[64 + d] = f2b(uv);
    row[128 + d] = f2b(u[(size_t)b * DD + d]);
  }
}

// ---------------------------------------------------------------------------
// MFMA MLP: 1 block, 512 threads (8 waves), all weights pre-staged behind one
// barrier. Proven (absmax 0.039 << 0.13).
// ---------------------------------------------------------------------------
template <int K, int WS, bool FIRST, bool LAST>
__device__ __forceinline__ void mlp_layer(int tid, const ushort* __restrict__ combg,
                                          float* hbuf, ushort* a_lds,
                                          const ushort* w_lds, const float* bias_s,
                                          float* ps, float* pq, float* ab, float* bb,
                                          const float* __restrict__ gamma,
                                          const float* __restrict__ beta,
                                          float* __restrict__ out) {
  const int lane = tid & 63, wv = tid >> 6;
  f32x4_t acc[2][4];
#pragma unroll
  for (int a = 0; a < 2; ++a)
#pragma unroll
    for (int nt = 0; nt < 4; ++nt) acc[a][nt] = (f32x4_t)(0.0f);

  const int m0 = wv * 32;
  const int r15 = lane & 15, kq = lane >> 4;
  for (int kk = 0; kk < K; kk += 32) {
    int koff = kk + kq * 8;
    bf16x8_t af[2], bf[4];
    if (FIRST) {
      const ushort* ap = combg + (size_t)(m0 + r15) * 192 + koff;
      af[0] = *reinterpret_cast<const bf16x8_t*>(ap);
      af[1] = *reinterpret_cast<const bf16x8_t*>(ap + 16 * 192);
    } else {
      const ushort* ap = &a_lds[(m0 + r15) * 72 + koff];
      af[0] = *reinterpret_cast<const bf16x8_t*>(ap);
      af[1] = *reinterpret_cast<const bf16x8_t*>(ap + 16 * 72);
    }
#pragma unroll
    for (int nt = 0; nt < 4; ++nt)
      bf[nt] = *reinterpret_cast<const bf16x8_t*>(&w_lds[(nt * 16 + r15) * WS + koff]);
#pragma unroll
    for (int a = 0; a < 2; ++a)
#pragma unroll
      for (int nt = 0; nt < 4; ++nt)
        acc[a][nt] = __builtin_amdgcn_mfma_f32_16x16x32_bf16(af[a], bf[nt], acc[a][nt], 0, 0, 0);
  }

#pragma unroll
  for (int a = 0; a < 2; ++a) {
#pragma unroll
    for (int nt = 0; nt < 4; ++nt) {
      int col = nt * 16 + r15;
#pragma unroll
      for (int j = 0; j < 4; ++j) {
        int row = m0 + a * 16 + kq * 4 + j;
        float v = acc[a][nt][j] + bias_s[col];
        hbuf[row * 65 + col] = fmaxf(v, 0.f);
      }
    }
  }
  __syncthreads();

  {
    int col = tid & 63, seg = tid >> 6;
    float s = 0.f, q = 0.f;
#pragma unroll
    for (int t = 0; t < 32; ++t) {
      float v = hbuf[(seg * 32 + t) * 65 + col];
      s += v;
      q += v * v;
    }
    ps[seg * 64 + col] = s;
    pq[seg * 64 + col] = q;
  }
  __syncthreads();
  if (tid < 64) {
    float s = 0.f, q = 0.f;
#pragma unroll
    for (int g = 0; g < 8; ++g) {
      s += ps[g * 64 + tid];
      q += pq[g * 64 + tid];
    }
    float mu = s * (1.0f / 256.0f);
    float var = q * (1.0f / 256.0f) - mu * mu;
    float rs = rsqrtf(var + 1e-5f);
    float A = gamma[tid] * rs;
    ab[tid] = A;
    bb[tid] = beta[tid] - mu * A;
  }
  __syncthreads();
  for (int i = tid; i < 256 * 64; i += 512) {
    int r = i >> 6, c = i & 63;
    float y = hbuf[r * 65 + c] * ab[c] + bb[c];
    if (LAST)
      out[i] = y;
    else
      a_lds[r * 72 + c] = f2b(y);
  }
  __syncthreads();
}

__global__ __launch_bounds__(512) void k_mlp(const ushort* __restrict__ comb,
                                             const float* W0, const float* b0,
                                             const float* W1, const float* b1,
                                             const float* W2, const float* b2,
                                             const float* g0, const float* be0,
                                             const float* g1, const float* be1,
                                             const float* g2, const float* be2,
                                             float* __restrict__ out) {
  __shared__ __align__(16) float hbuf[256 * 65];    // 66.6 KB
  __shared__ __align__(16) ushort a_lds[256 * 72];  // 36.9 KB
  __shared__ __align__(16) ushort w0s[64 * 200];    // 25.6 KB
  __shared__ __align__(16) ushort w1s[64 * 72];     // 9.2 KB
  __shared__ __align__(16) ushort w2s[64 * 72];     // 9.2 KB
  __shared__ float ps[8 * 64], pq[8 * 64];
  __shared__ float b0s[64], b1s[64], b2s[64], ab[64], bb[64];
  int tid = threadIdx.x;

  for (int i = tid; i < 64 * 192; i += 512) {
    int r = i / 192, c = i - r * 192;
    w0s[r * 200 + c] = f2b(W0[i]);
  }
  for (int i = tid; i < 64 * 64; i += 512) {
    int r = i >> 6, c = i & 63;
    w1s[r * 72 + c] = f2b(W1[i]);
    w2s[r * 72 + c] = f2b(W2[i]);
  }
  if (tid < 64) {
    b0s[tid] = b0[tid];
    b1s[tid] = b1[tid];
    b2s[tid] = b2[tid];
  }
  __syncthreads();

  mlp_layer<192, 200, true, false>(tid, comb, hbuf, a_lds, w0s, b0s, ps, pq, ab, bb,
                                   g0, be0, nullptr);
  mlp_layer<64, 72, false, false>(tid, comb, hbuf, a_lds, w1s, b1s, ps, pq, ab, bb,
                                  g1, be1, nullptr);
  mlp_layer<64, 72, false, true>(tid, comb, hbuf, a_lds, w2s, b2s, ps, pq, ab, bb,
                                 g2, be2, out);
}

extern "C" void kernel_launch(void* const* d_in, const int* in_sizes, int n_in,
                              void* d_out, int out_size, void* d_ws, size_t ws_size,
                              hipStream_t stream) {
  (void)n_in; (void)out_size; (void)ws_size;
  const float* x         = (const float*)d_in[0];
  const float* edge_attr = (const float*)d_in[1];
  const float* u         = (const float*)d_in[2];
  const int*   eidx      = (const int*)d_in[3];  // row 0 = first E entries
  const int*   batch     = (const int*)d_in[4];
  const float* W0 = (const float*)d_in[5];
  const float* b0 = (const float*)d_in[6];
  const float* W1 = (const float*)d_in[7];
  const float* b1 = (const float*)d_in[8];
  const float* W2 = (const float*)d_in[9];
  const float* b2 = (const float*)d_in[10];
  const float* g0 = (const float*)d_in[11];
  const float* be0 = (const float*)d_in[12];
  const float* g1 = (const float*)d_in[13];
  const float* be1 = (const float*)d_in[14];
  const float* g2 = (const float*)d_in[15];
  const float* be2 = (const float*)d_in[16];

  int N = in_sizes[0] / DD;
  int E = in_sizes[1] / DD;

  // ws layout (16B padded): partial[NEB*GB*64] f32 (16.7MB) | cnt[N] | comb
  float* partial = (float*)d_ws;
  int* cnt = (int*)(partial + (size_t)NEB * GB * DD);
  ushort* comb = (ushort*)(cnt + ((N + 3) & ~3));

  k_zero<<<64, 256, 0, stream>>>(cnt, N);
  k_hist<<<1024, 256, 0, stream>>>(eidx, cnt, E);
  k_edgesum<<<NEB, 512, 0, stream>>>(edge_attr, eidx, cnt, batch, partial, E);
  k_reduce<<<256, 256, 0, stream>>>(partial, x, u, batch, comb, N);
  k_mlp<<<1, 512, 0, stream>>>(comb, W0, b0, W1, b1, W2, b2,
                               g0, be0, g1, be1, g2, be2, (float*)d_out);
}

// Round 13
// 136.093 us; speedup vs baseline: 1.3810x; 1.0506x over previous
//
#include <hip/hip_runtime.h>
#include <hip/hip_bf16.h>

#define DD 64
#define ECH 128     // edges per chunk (one-hot GEMM K)
#define NEB 256     // edgesum blocks (1 per CU)
#define GB 256      // graph bins (B==256)
#define MAXPER 3200 // 25 chunks * 128 >= ceil(E/NEB)=3125

typedef __attribute__((ext_vector_type(8))) short bf16x8_t;
typedef __attribute__((ext_vector_type(4))) float f32x4_t;

__device__ __forceinline__ ushort f2b(float x) {
  __hip_bfloat16 h = __float2bfloat16(x);
  ushort r;
  __builtin_memcpy(&r, &h, 2);
  return r;
}

// XOR swizzle for 256B-row LDS tiles. h = (row&7) ^ ((row>>3)&7):
//  * fragment reads (16 consecutive rows per lane-group): h hits each value
//    twice -> 2-way (free)
//  * transpose writes (row stride 8 within an instruction): (row>>3) varies
//    -> 8 distinct h -> banks spread, 2-way (free).  [R12's (row&7)-only
//    swizzle left writes 8-way conflicted: constant per instruction.]
__device__ __forceinline__ uint swz(uint b) {
  return b ^ (((((b >> 8) & 7u)) ^ ((b >> 11) & 7u)) << 4);
}

__global__ __launch_bounds__(256) void k_zero(int* __restrict__ p, int n) {
  int gid = blockIdx.x * blockDim.x + threadIdx.x;
  int stride = gridDim.x * blockDim.x;
  for (int i = gid; i < n; i += stride) p[i] = 0;
}

__global__ __launch_bounds__(256) void k_hist(const int* __restrict__ eidx,
                                              int* __restrict__ cnt, int E) {
  int gid = blockIdx.x * blockDim.x + threadIdx.x;
  int stride = gridDim.x * blockDim.x;
  int E4 = E >> 2;
  const int4* e4 = reinterpret_cast<const int4*>(eidx);
  for (int i = gid; i < E4; i += stride) {
    int4 v = e4[i];
    atomicAdd(&cnt[v.x], 1);
    atomicAdd(&cnt[v.y], 1);
    atomicAdd(&cnt[v.z], 1);
    atomicAdd(&cnt[v.w], 1);
  }
  for (int e = (E4 << 2) + gid; e < E; e += stride) atomicAdd(&cnt[eidx[e]], 1);
}

// ---------------------------------------------------------------------------
// Edge -> graph-bin accumulation as ONE-HOT GEMM per chunk (R12 structure):
//   C[256 bins][64 dims] += S[256][128] * V  where S[b][e] = w_e one-hot.
// R13 deltas:
//  * swizzle fix (see swz) -> Vt transpose writes conflict-free
//  * SPLIT-K: waves 0-3 own K 0..63, waves 4-7 own K 64..127; each wave
//    computes 64 bins x 64 dims (4 m-tiles) -> 16 fragment reads/chunk/wave
//    (was 24). Wave pairs merge through LDS (S reused) at epilogue.
// LDS: S 64KB + Vt 16KB + meta 25.6KB = 105.6KB -> 1 block/CU.
// ---------------------------------------------------------------------------
__global__ __launch_bounds__(512) void k_edgesum(const float* __restrict__ edge_attr,
                                                 const int* __restrict__ eidx,
                                                 const int* __restrict__ cnt,
                                                 const int* __restrict__ batch,
                                                 float* __restrict__ partial, int E) {
  __shared__ ushort S[256 * 128];  // 64 KB, rows = bins, 256B/row
  __shared__ ushort Vt[64 * 128];  // 16 KB, rows = dims,  256B/row
  __shared__ int2 meta[MAXPER];    // 25.6 KB
  const int tid = threadIdx.x;
  const int lane = tid & 63, wv = tid >> 6;
  const int r15 = lane & 15, kq = lane >> 4;
  const int kh = wv >> 2;  // K-half this wave contracts (0: e 0..63, 1: 64..127)
  const int mq = wv & 3;   // bin quadrant: bins [mq*64, mq*64+64)

  const int per = (E + NEB - 1) / NEB;        // 3125
  const int base = blockIdx.x * per;
  const int nE = max(0, min(per, E - base));
  const int nch = (nE + ECH - 1) / ECH;       // 25

  const int e0 = (tid >> 3) * 2;  // edge pair owned by this thread
  const int d0 = (tid & 7) * 8;   // dim group owned by this thread

  float4 rA[4], rB[4];

#define LOADC(c, R)                                                              \
  do {                                                                           \
    size_t r0_ = (size_t)min(base + (c)*ECH + e0, E - 1);                        \
    size_t r1_ = (size_t)min(base + (c)*ECH + e0 + 1, E - 1);                    \
    const float4* p0_ = reinterpret_cast<const float4*>(edge_attr + r0_ * DD + d0); \
    const float4* p1_ = reinterpret_cast<const float4*>(edge_attr + r1_ * DD + d0); \
    R[0] = p0_[0];                                                               \
    R[1] = p0_[1];                                                               \
    R[2] = p1_[0];                                                               \
    R[3] = p1_[1];                                                               \
  } while (0)

#define PHASEW(c, R)                                                             \
  do {                                                                           \
    _Pragma("unroll") for (int q = 0; q < 2; ++q) {                              \
      _Pragma("unroll") for (int j = 0; j < 4; ++j) {                            \
        int d_ = d0 + q * 4 + j;                                                 \
        uint w32_ = (uint)f2b(((const float*)&R[q])[j]) |                        \
                    ((uint)f2b(((const float*)&R[2 + q])[j]) << 16);             \
        *(uint*)((char*)Vt + swz(((uint)d_ * 128 + e0) * 2)) = w32_;             \
      }                                                                          \
    }                                                                            \
    if (tid < ECH) {                                                             \
      if (prev >= 0) *(ushort*)((char*)S + swz(((uint)prev * 128 + tid) * 2)) = 0; \
      int2 mm_ = meta[(c)*ECH + tid];                                            \
      if (mm_.x >= 0) {                                                          \
        *(ushort*)((char*)S + swz(((uint)mm_.x * 128 + tid) * 2)) =              \
            f2b(__int_as_float(mm_.y));                                          \
        prev = mm_.x;                                                            \
      } else {                                                                   \
        prev = -1;                                                               \
      }                                                                          \
    }                                                                            \
  } while (0)

// split-K MFMA phase: this wave's 2 k-steps over 4 m-tiles x 4 n-tiles
#define MFMAP()                                                                  \
  do {                                                                           \
    _Pragma("unroll") for (int ks = 0; ks < 2; ++ks) {                           \
      uint ko_ = (uint)((kh * 2 + ks) * 32 + kq * 8) * 2;                        \
      bf16x8_t b0_ = *(const bf16x8_t*)((const char*)Vt + swz((uint)(r15)*256 + ko_)); \
      bf16x8_t b1_ = *(const bf16x8_t*)((const char*)Vt +                        \
                                        swz((uint)(16 + r15) * 256 + ko_));      \
      bf16x8_t b2_ = *(const bf16x8_t*)((const char*)Vt +                        \
                                        swz((uint)(32 + r15) * 256 + ko_));      \
      bf16x8_t b3_ = *(const bf16x8_t*)((const char*)Vt +                        \
                                        swz((uint)(48 + r15) * 256 + ko_));      \
      _Pragma("unroll") for (int mt = 0; mt < 4; ++mt) {                         \
        bf16x8_t a_ = *(const bf16x8_t*)((const char*)S +                        \
                                         swz((uint)(mq * 64 + mt * 16 + r15) * 256 + ko_)); \
        acc[mt][0] = __builtin_amdgcn_mfma_f32_16x16x32_bf16(a_, b0_, acc[mt][0], 0, 0, 0); \
        acc[mt][1] = __builtin_amdgcn_mfma_f32_16x16x32_bf16(a_, b1_, acc[mt][1], 0, 0, 0); \
        acc[mt][2] = __builtin_amdgcn_mfma_f32_16x16x32_bf16(a_, b2_, acc[mt][2], 0, 0, 0); \
        acc[mt][3] = __builtin_amdgcn_mfma_f32_16x16x32_bf16(a_, b3_, acc[mt][3], 0, 0, 0); \
      }                                                                          \
    }                                                                            \
  } while (0)

#define LGKM0() asm volatile("s_waitcnt lgkmcnt(0)" ::: "memory")

  f32x4_t acc[4][4];
#pragma unroll
  for (int a = 0; a < 4; ++a)
#pragma unroll
    for (int nt = 0; nt < 4; ++nt) acc[a][nt] = (f32x4_t)(0.0f);

  // prologue: fire chunk 0/1 loads early, then meta + S zero
  LOADC(0, rA);
  if (nch > 1) LOADC(1, rB);
  for (int i = tid; i < 256 * 128 / 2; i += 512) ((uint*)S)[i] = 0u;
  for (int i = tid; i < MAXPER; i += 512) {
    int pb = -1;
    float pw = 0.f;
    if (i < nE) {
      int n = eidx[base + i];
      pw = 1.0f / fmaxf((float)cnt[n], 1.0f);
      pb = batch[n];
    }
    meta[i] = make_int2(pb, __float_as_int(pw));
  }
  int prev = -1;
  __syncthreads();

  for (int c = 0; c < nch; c += 2) {
    PHASEW(c, rA);
    LGKM0();
    __builtin_amdgcn_s_barrier();
    if (c + 2 < nch) LOADC(c + 2, rA);
    MFMAP();
    LGKM0();
    __builtin_amdgcn_s_barrier();
    if (c + 1 < nch) {
      PHASEW(c + 1, rB);
      LGKM0();
      __builtin_amdgcn_s_barrier();
      if (c + 3 < nch) LOADC(c + 3, rB);
      MFMAP();
      LGKM0();
      __builtin_amdgcn_s_barrier();
    }
  }

  // epilogue: merge K-half partials through LDS (S is free now), then store.
  // D layout (16x16x32): col = lane&15, row = (lane>>4)*4 + j  [m89]
  __syncthreads();
  float* Smrg = (float*)S;  // 256*64 f32 = 64KB
  if (kh == 0) {
#pragma unroll
    for (int mt = 0; mt < 4; ++mt)
#pragma unroll
      for (int nt = 0; nt < 4; ++nt)
#pragma unroll
        for (int j = 0; j < 4; ++j)
          Smrg[(mq * 64 + mt * 16 + kq * 4 + j) * 64 + nt * 16 + r15] = acc[mt][nt][j];
  }
  __syncthreads();
  if (kh == 1) {
    float* outp = partial + (size_t)blockIdx.x * GB * DD;
#pragma unroll
    for (int mt = 0; mt < 4; ++mt)
#pragma unroll
      for (int nt = 0; nt < 4; ++nt)
#pragma unroll
        for (int j = 0; j < 4; ++j) {
          int idx = (mq * 64 + mt * 16 + kq * 4 + j) * 64 + nt * 16 + r15;
          outp[idx] = Smrg[idx] + acc[mt][nt][j];
        }
  }
#undef LOADC
#undef PHASEW
#undef MFMAP
#undef LGKM0
}

// ---------------------------------------------------------------------------
// Per-graph: reduce NEB partials + pool x + copy u -> bf16 comb row.
// ---------------------------------------------------------------------------
__global__ __launch_bounds__(256) void k_reduce(const float* __restrict__ partial,
                                                const float* __restrict__ x,
                                                const float* __restrict__ u,
                                                const int* __restrict__ batch,
                                                ushort* __restrict__ comb, int N) {
  __shared__ int s_lo, s_hi;
  __shared__ float rE[4][64], rV[4][64];
  int b = blockIdx.x;
  int tid = threadIdx.x;
  if (tid == 0) {
    int lo = 0, hi = N;
    while (lo < hi) { int m = (lo + hi) >> 1; if (batch[m] < b) lo = m + 1; else hi = m; }
    s_lo = lo;
    hi = N;
    while (lo < hi) { int m = (lo + hi) >> 1; if (batch[m] < b + 1) lo = m + 1; else hi = m; }
    s_hi = lo;
  }
  __syncthreads();
  int lo = s_lo, hi = s_hi;
  int d = tid & 63, sub = tid >> 6;
  float accE = 0.f, accV = 0.f;
  for (int p = sub; p < NEB; p += 4)
    accE += partial[((size_t)p * GB + b) * DD + d];
  for (int n = lo + sub; n < hi; n += 4)
    accV += x[(size_t)n * DD + d];
  rE[sub][d] = accE;
  rV[sub][d] = accV;
  __syncthreads();
  if (sub == 0) {
    float invNb = 1.0f / fmaxf((float)(hi - lo), 1.0f);
    float ue = (rE[0][d] + rE[1][d] + rE[2][d] + rE[3][d]) * invNb;
    float uv = (rV[0][d] + rV[1][d] + rV[2][d] + rV[3][d]) * invNb;
    ushort* row = comb + (size_t)b * 192;
    row[d] = f2b(ue);
    row[64 + d] = f2b(uv);
    row[128 + d] = f2b(u[(size_t)b * DD + d]);
  }
}

// ---------------------------------------------------------------------------
// MFMA MLP: 1 block, 512 threads (8 waves), all weights pre-staged behind one
// barrier. Proven (absmax 0.039 << 0.13).
// ---------------------------------------------------------------------------
template <int K, int WS, bool FIRST, bool LAST>
__device__ __forceinline__ void mlp_layer(int tid, const ushort* __restrict__ combg,
                                          float* hbuf, ushort* a_lds,
                                          const ushort* w_lds, const float* bias_s,
                                          float* ps, float* pq, float* ab, float* bb,
                                          const float* __restrict__ gamma,
                                          const float* __restrict__ beta,
                                          float* __restrict__ out) {
  const int lane = tid & 63, wv = tid >> 6;
  f32x4_t acc[2][4];
#pragma unroll
  for (int a = 0; a < 2; ++a)
#pragma unroll
    for (int nt = 0; nt < 4; ++nt) acc[a][nt] = (f32x4_t)(0.0f);

  const int m0 = wv * 32;
  const int r15 = lane & 15, kq = lane >> 4;
  for (int kk = 0; kk < K; kk += 32) {
    int koff = kk + kq * 8;
    bf16x8_t af[2], bf[4];
    if (FIRST) {
      const ushort* ap = combg + (size_t)(m0 + r15) * 192 + koff;
      af[0] = *reinterpret_cast<const bf16x8_t*>(ap);
      af[1] = *reinterpret_cast<const bf16x8_t*>(ap + 16 * 192);
    } else {
      const ushort* ap = &a_lds[(m0 + r15) * 72 + koff];
      af[0] = *reinterpret_cast<const bf16x8_t*>(ap);
      af[1] = *reinterpret_cast<const bf16x8_t*>(ap + 16 * 72);
    }
#pragma unroll
    for (int nt = 0; nt < 4; ++nt)
      bf[nt] = *reinterpret_cast<const bf16x8_t*>(&w_lds[(nt * 16 + r15) * WS + koff]);
#pragma unroll
    for (int a = 0; a < 2; ++a)
#pragma unroll
      for (int nt = 0; nt < 4; ++nt)
        acc[a][nt] = __builtin_amdgcn_mfma_f32_16x16x32_bf16(af[a], bf[nt], acc[a][nt], 0, 0, 0);
  }

#pragma unroll
  for (int a = 0; a < 2; ++a) {
#pragma unroll
    for (int nt = 0; nt < 4; ++nt) {
      int col = nt * 16 + r15;
#pragma unroll
      for (int j = 0; j < 4; ++j) {
        int row = m0 + a * 16 + kq * 4 + j;
        float v = acc[a][nt][j] + bias_s[col];
        hbuf[row * 65 + col] = fmaxf(v, 0.f);
      }
    }
  }
  __syncthreads();

  {
    int col = tid & 63, seg = tid >> 6;
    float s = 0.f, q = 0.f;
#pragma unroll
    for (int t = 0; t < 32; ++t) {
      float v = hbuf[(seg * 32 + t) * 65 + col];
      s += v;
      q += v * v;
    }
    ps[seg * 64 + col] = s;
    pq[seg * 64 + col] = q;
  }
  __syncthreads();
  if (tid < 64) {
    float s = 0.f, q = 0.f;
#pragma unroll
    for (int g = 0; g < 8; ++g) {
      s += ps[g * 64 + tid];
      q += pq[g * 64 + tid];
    }
    float mu = s * (1.0f / 256.0f);
    float var = q * (1.0f / 256.0f) - mu * mu;
    float rs = rsqrtf(var + 1e-5f);
    float A = gamma[tid] * rs;
    ab[tid] = A;
    bb[tid] = beta[tid] - mu * A;
  }
  __syncthreads();
  for (int i = tid; i < 256 * 64; i += 512) {
    int r = i >> 6, c = i & 63;
    float y = hbuf[r * 65 + c] * ab[c] + bb[c];
    if (LAST)
      out[i] = y;
    else
      a_lds[r * 72 + c] = f2b(y);
  }
  __syncthreads();
}

__global__ __launch_bounds__(512) void k_mlp(const ushort* __restrict__ comb,
                                             const float* W0, const float* b0,
                                             const float* W1, const float* b1,
                                             const float* W2, const float* b2,
                                             const float* g0, const float* be0,
                                             const float* g1, const float* be1,
                                             const float* g2, const float* be2,
                                             float* __restrict__ out) {
  __shared__ __align__(16) float hbuf[256 * 65];    // 66.6 KB
  __shared__ __align__(16) ushort a_lds[256 * 72];  // 36.9 KB
  __shared__ __align__(16) ushort w0s[64 * 200];    // 25.6 KB
  __shared__ __align__(16) ushort w1s[64 * 72];     // 9.2 KB
  __shared__ __align__(16) ushort w2s[64 * 72];     // 9.2 KB
  __shared__ float ps[8 * 64], pq[8 * 64];
  __shared__ float b0s[64], b1s[64], b2s[64], ab[64], bb[64];
  int tid = threadIdx.x;

  for (int i = tid; i < 64 * 192; i += 512) {
    int r = i / 192, c = i - r * 192;
    w0s[r * 200 + c] = f2b(W0[i]);
  }
  for (int i = tid; i < 64 * 64; i += 512) {
    int r = i >> 6, c = i & 63;
    w1s[r * 72 + c] = f2b(W1[i]);
    w2s[r * 72 + c] = f2b(W2[i]);
  }
  if (tid < 64) {
    b0s[tid] = b0[tid];
    b1s[tid] = b1[tid];
    b2s[tid] = b2[tid];
  }
  __syncthreads();

  mlp_layer<192, 200, true, false>(tid, comb, hbuf, a_lds, w0s, b0s, ps, pq, ab, bb,
                                   g0, be0, nullptr);
  mlp_layer<64, 72, false, false>(tid, comb, hbuf, a_lds, w1s, b1s, ps, pq, ab, bb,
                                  g1, be1, nullptr);
  mlp_layer<64, 72, false, true>(tid, comb, hbuf, a_lds, w2s, b2s, ps, pq, ab, bb,
                                 g2, be2, out);
}

extern "C" void kernel_launch(void* const* d_in, const int* in_sizes, int n_in,
                              void* d_out, int out_size, void* d_ws, size_t ws_size,
                              hipStream_t stream) {
  (void)n_in; (void)out_size; (void)ws_size;
  const float* x         = (const float*)d_in[0];
  const float* edge_attr = (const float*)d_in[1];
  const float* u         = (const float*)d_in[2];
  const int*   eidx      = (const int*)d_in[3];  // row 0 = first E entries
  const int*   batch     = (const int*)d_in[4];
  const float* W0 = (const float*)d_in[5];
  const float* b0 = (const float*)d_in[6];
  const float* W1 = (const float*)d_in[7];
  const float* b1 = (const float*)d_in[8];
  const float* W2 = (const float*)d_in[9];
  const float* b2 = (const float*)d_in[10];
  const float* g0 = (const float*)d_in[11];
  const float* be0 = (const float*)d_in[12];
  const float* g1 = (const float*)d_in[13];
  const float* be1 = (const float*)d_in[14];
  const float* g2 = (const float*)d_in[15];
  const float* be2 = (const float*)d_in[16];

  int N = in_sizes[0] / DD;
  int E = in_sizes[1] / DD;

  // ws layout (16B padded): partial[NEB*GB*64] f32 (16.7MB) | cnt[N] | comb
  float* partial = (float*)d_ws;
  int* cnt = (int*)(partial + (size_t)NEB * GB * DD);
  ushort* comb = (ushort*)(cnt + ((N + 3) & ~3));

  k_zero<<<64, 256, 0, stream>>>(cnt, N);
  k_hist<<<1024, 256, 0, stream>>>(eidx, cnt, E);
  k_edgesum<<<NEB, 512, 0, stream>>>(edge_attr, eidx, cnt, batch, partial, E);
  k_reduce<<<256, 256, 0, stream>>>(partial, x, u, batch, comb, N);
  k_mlp<<<1, 512, 0, stream>>>(comb, W0, b0, W1, b1, W2, b2,
                               g0, be0, g1, be1, g2, be2, (float*)d_out);
}